// Round 6
// baseline (184.332 us; speedup 1.0000x reference)
//
#include <hip/hip_runtime.h>
#include <math.h>

// Problem constants
#define KC 1024       // num codes
#define DD 256        // embedding dim
#define NROWS 32768   // 32 * 32 * 32 (B*H*W)
#define NELEM 8388608 // NROWS * DD

typedef _Float16 f16;
typedef __attribute__((ext_vector_type(8))) _Float16 f16x8;
typedef __attribute__((ext_vector_type(16))) float f32x16;

#define KEY_SCALE 2097152.0f   // 2^21; |score| <= ~0.63 -> |ikey| < 2^21
#define KEY_INV   (1.0f / 2097152.0f)

// ---------------------------------------------------------------------------
// prep: zero counts/loss/done + c_sq (exact fp32) + emb -> fp16 swizzled
// grid 256 x 256.  emb_h layout: [kg 32][code 1024][8]
// ---------------------------------------------------------------------------
__global__ void vq_prep_kernel(const float* __restrict__ emb, f16* __restrict__ emb_h,
                               float* __restrict__ c_sq, int* __restrict__ counts,
                               float* __restrict__ loss_acc, unsigned* __restrict__ done) {
    const int tid = threadIdx.x;
    const int gt = blockIdx.x * 256 + tid;
    if (gt < KC) counts[gt] = 0;
    if (gt == 0) { *loss_acc = 0.0f; *done = 0u; }
    {
        int k = blockIdx.x * 4 + (tid >> 6);
        int lane = tid & 63;
        float4 v = *(const float4*)(emb + (size_t)k * DD + lane * 4);
        float s = v.x * v.x + v.y * v.y + v.z * v.z + v.w * v.w;
        #pragma unroll
        for (int off = 32; off > 0; off >>= 1) s += __shfl_down(s, off);
        if (lane == 0) c_sq[k] = s;
    }
    if (gt < 32768) {
        int code = gt & 1023;
        int kg = gt >> 10;
        const float* p = emb + (size_t)code * DD + kg * 8;
        float4 v0 = *(const float4*)p;
        float4 v1 = *(const float4*)(p + 4);
        f16x8 h;
        h[0] = (f16)v0.x; h[1] = (f16)v0.y; h[2] = (f16)v0.z; h[3] = (f16)v0.w;
        h[4] = (f16)v1.x; h[5] = (f16)v1.y; h[6] = (f16)v1.z; h[7] = (f16)v1.w;
        *(f16x8*)(emb_h + (size_t)gt * 8) = h;
    }
}

// ---------------------------------------------------------------------------
// Fused main: dist (MFMA, B-frag register-ring prefetch) + packed-int argmin
// + loss-from-score + register-transpose gather epilogue + last-block final.
// Block = 64 rows x 512 threads (8 waves), grid 512 -> 2 blocks/CU.
// Wave w owns codes [w*128,(w+1)*128) as 4 chunks of 32; per k-step the
// B-fragment was loaded 4 iterations ago (vmcnt never drains to 0 mid-loop).
// argmin key = trunc(score*2^21)*1024 + code.  loss row = score_min + ||z||^2.
// ---------------------------------------------------------------------------
__global__ __launch_bounds__(512, 4)
void vq_main_kernel(const float* __restrict__ z, const float* __restrict__ emb,
                    const f16* __restrict__ emb_h, const float* __restrict__ c_sq,
                    int* __restrict__ counts, float* __restrict__ loss_acc,
                    unsigned* __restrict__ done, float* __restrict__ out,
                    float* __restrict__ out_tail) {
    __shared__ __align__(16) f16 z_s[16384];   // [kg 32][row 64][8]
    __shared__ int   bl_key[8][64];
    __shared__ float zsq_part[8][64];
    __shared__ int   idx_s[64];
    __shared__ float wsum[8];
    __shared__ int   last_flag;

    const int tid = threadIdx.x;
    const int n0 = blockIdx.x * 64;
    const int b = n0 >> 10;
    const int hw0 = n0 & 1023;

    const int m = tid & 31;        // code-lane within 32-tile
    const int h = (tid >> 5) & 1;  // k-half
    const int w = tid >> 6;        // wave id 0..7

    // B-fragment base for this lane (emb_h: [kg 32][code 1024][8])
    const f16* ebase = emb_h + (size_t)h * 8192 + (size_t)(w * 128 + m) * 8;

    // ---- Phase A: stage z tile fp16 + per-row ||z||^2 partials ----
    {
        const int r = tid & 63;
        const int kq = tid >> 6;  // 0..7
        const float* zp = z + (size_t)b * (DD * 1024) + hw0 + r;
        float sq = 0.f;
        #pragma unroll
        for (int it = 0; it < 4; ++it) {
            int kg = kq * 4 + it;
            f16x8 hv;
            #pragma unroll
            for (int j = 0; j < 8; ++j) {
                float v = zp[(size_t)(kg * 8 + j) * 1024];
                sq += v * v;
                hv[j] = (f16)v;
            }
            *(f16x8*)&z_s[(kg * 64 + r) * 8] = hv;
        }
        zsq_part[kq][r] = sq;
    }

    // preload B-frag ring (chunk 0, ks 0..3) -- flies through the barrier
    f16x8 bF[4];
    #pragma unroll
    for (int p = 0; p < 4; ++p) bF[p] = *(const f16x8*)(ebase + (size_t)p * 16384);

    __syncthreads();

    int bk[32];
    #pragma unroll
    for (int s = 0; s < 32; ++s) bk[s] = 0x7FFFFFFF;

    // ---- Phase B: MFMA + ring prefetch + running packed argmin ----
    for (int c = 0; c < 4; ++c) {
        const int code = w * 128 + c * 32 + m;

        f32x16 acc0, acc1;
        #pragma unroll
        for (int i = 0; i < 16; ++i) { acc0[i] = 0.f; acc1[i] = 0.f; }

        #pragma unroll
        for (int ks = 0; ks < 16; ++ks) {
            f16x8 bcur = bF[ks & 3];
            // refill slot with step ks+4 (crosses into chunk c+1 for ks>=12;
            // at c==3 this reads ~0.5KB past emb_h into ws scratch -- loaded
            // but never consumed, always in-bounds of d_ws)
            {
                const int pf = ks + 4;
                bF[ks & 3] = *(const f16x8*)(ebase + (size_t)(c + (pf >> 4)) * 256
                                                   + (size_t)(pf & 15) * 16384);
            }
            const f16* za = z_s + (2 * ks + h) * 512 + m * 8;
            f16x8 a0 = *(const f16x8*)(za);          // rows m
            f16x8 a1 = *(const f16x8*)(za + 256);    // rows m+32
            acc0 = __builtin_amdgcn_mfma_f32_32x32x16_f16(a0, bcur, acc0, 0, 0, 0);
            acc1 = __builtin_amdgcn_mfma_f32_32x32x16_f16(a1, bcur, acc1, 0, 0, 0);
        }

        const float cs = c_sq[code];
        #pragma unroll
        for (int reg = 0; reg < 16; ++reg) {
            float s0 = fmaf(-2.f, acc0[reg], cs);
            float s1 = fmaf(-2.f, acc1[reg], cs);
            int k0 = (int)(s0 * KEY_SCALE) * 1024 + code;
            int k1 = (int)(s1 * KEY_SCALE) * 1024 + code;
            bk[reg] = min(bk[reg], k0);
            bk[16 + reg] = min(bk[16 + reg], k1);
        }
    }

    // butterfly min across 32 lanes of each half
    #pragma unroll
    for (int s = 0; s < 32; ++s) {
        int k = bk[s];
        #pragma unroll
        for (int d = 16; d >= 1; d >>= 1) k = min(k, __shfl_xor(k, d));
        bk[s] = k;
    }
    if (m == 0) {
        #pragma unroll
        for (int s = 0; s < 32; ++s) {
            int rt = s >> 4, reg = s & 15;
            int row = rt * 32 + (reg & 3) + 8 * (reg >> 2) + 4 * h;
            bl_key[w][row] = bk[s];
        }
    }
    __syncthreads();

    // combine 8 waves -> idx, hist, loss-from-score
    if (tid < 64) {
        int k = bl_key[0][tid];
        #pragma unroll
        for (int w2 = 1; w2 < 8; ++w2) k = min(k, bl_key[w2][tid]);
        int i = k & 1023;
        idx_s[tid] = i;
        atomicAdd(&counts[i], 1);
        float zq = 0.f;
        #pragma unroll
        for (int p = 0; p < 8; ++p) zq += zsq_part[p][tid];
        float lr = (float)(k >> 10) * KEY_INV + zq;  // score_min + ||z||^2
        #pragma unroll
        for (int off = 32; off > 0; off >>= 1) lr += __shfl_down(lr, off);
        if (tid == 0) atomicAdd(loss_acc, lr);
    }
    __syncthreads();

    // ---- Phase C: per-thread gather + in-register 4x8 transpose + float4
    // stores along hw (no LDS round-trip, no extra barrier) ----
    {
        const int rgrp = tid & 15;       // rows rgrp*4 .. +3
        const int cg = tid >> 4;         // channels cg*8 .. +7
        float4 e0[4], e1[4];
        #pragma unroll
        for (int i = 0; i < 4; ++i) {
            const float* ep = emb + (size_t)idx_s[rgrp * 4 + i] * DD + cg * 8;
            e0[i] = *(const float4*)ep;
            e1[i] = *(const float4*)(ep + 4);
        }
        const size_t base = (size_t)b * (DD * 1024) + hw0 + rgrp * 4;
        #pragma unroll
        for (int j = 0; j < 4; ++j) {
            float4 st;
            st.x = (&e0[0].x)[j]; st.y = (&e0[1].x)[j];
            st.z = (&e0[2].x)[j]; st.w = (&e0[3].x)[j];
            *(float4*)(out + base + (size_t)(cg * 8 + j) * 1024) = st;
        }
        #pragma unroll
        for (int j = 0; j < 4; ++j) {
            float4 st;
            st.x = (&e1[0].x)[j]; st.y = (&e1[1].x)[j];
            st.z = (&e1[2].x)[j]; st.w = (&e1[3].x)[j];
            *(float4*)(out + base + (size_t)(cg * 8 + 4 + j) * 1024) = st;
        }
    }

    // ---- last-block finalize ----
    __syncthreads();
    if (tid == 0) {
        __threadfence();
        last_flag = (atomicAdd(done, 1u) == 511u) ? 1 : 0;
    }
    __syncthreads();
    if (last_flag) {
        __threadfence();
        float s = 0.f;
        for (int k = tid; k < KC; k += 512) {
            int cnt = atomicAdd(&counts[k], 0);
            float p = (float)cnt * (1.0f / (float)NROWS);
            s += p * logf(p + 1e-10f);
        }
        #pragma unroll
        for (int off = 32; off > 0; off >>= 1) s += __shfl_down(s, off);
        if ((tid & 63) == 0) wsum[w] = s;
        __syncthreads();
        if (tid == 0) {
            float ent = 0.f;
            #pragma unroll
            for (int p = 0; p < 8; ++p) ent += wsum[p];
            float ls = atomicAdd(loss_acc, 0.0f);
            out_tail[0] = 1.25f * ls * (1.0f / (float)NELEM);
            out_tail[1] = expf(-ent);
        }
    }
}

// ---------------------------------------------------------------------------
extern "C" void kernel_launch(void* const* d_in, const int* in_sizes, int n_in,
                              void* d_out, int out_size, void* d_ws, size_t ws_size,
                              hipStream_t stream) {
    const float* z = (const float*)d_in[0];    // (32,256,32,32)
    const float* emb = (const float*)d_in[1];  // (1024,256)
    float* out = (float*)d_out;                // 8388608 + 2

    char* wsb = (char*)d_ws;
    f16* emb_h = (f16*)wsb;                    // 524288 B (+ prefetch slop below)
    float* c_sq = (float*)(wsb + 524288);
    int* counts = (int*)(wsb + 528384);
    float* loss_acc = (float*)(wsb + 532480);
    unsigned* done = (unsigned*)(wsb + 532484);

    hipLaunchKernelGGL(vq_prep_kernel, dim3(256), dim3(256), 0, stream,
                       emb, emb_h, c_sq, counts, loss_acc, done);
    hipLaunchKernelGGL(vq_main_kernel, dim3(512), dim3(512), 0, stream,
                       z, emb, emb_h, c_sq, counts, loss_acc, done, out, out + NELEM);
}

// Round 7
// 135.312 us; speedup vs baseline: 1.3623x; 1.3623x over previous
//
#include <hip/hip_runtime.h>
#include <math.h>

// Problem constants
#define KC 1024       // num codes
#define DD 256        // embedding dim
#define NROWS 32768   // 32 * 32 * 32 (B*H*W)
#define NELEM 8388608 // NROWS * DD

typedef _Float16 f16;
typedef __attribute__((ext_vector_type(8))) _Float16 f16x8;
typedef __attribute__((ext_vector_type(16))) float f32x16;

#define KEY_SCALE 2097152.0f   // 2^21; |score| <= ~0.63 -> |ikey| < 2^21
#define KEY_INV   (1.0f / 2097152.0f)

// ---------------------------------------------------------------------------
// prep: zero counts/loss/done + c_sq (exact fp32) + emb -> fp16 swizzled
// grid 256 x 256.  emb_h layout: [kg 32][code 1024][8]
// ---------------------------------------------------------------------------
__global__ void vq_prep_kernel(const float* __restrict__ emb, f16* __restrict__ emb_h,
                               float* __restrict__ c_sq, int* __restrict__ counts,
                               float* __restrict__ loss_acc, unsigned* __restrict__ done) {
    const int tid = threadIdx.x;
    const int gt = blockIdx.x * 256 + tid;
    if (gt < KC) counts[gt] = 0;
    if (gt == 0) { *loss_acc = 0.0f; *done = 0u; }
    {
        int k = blockIdx.x * 4 + (tid >> 6);
        int lane = tid & 63;
        float4 v = *(const float4*)(emb + (size_t)k * DD + lane * 4);
        float s = v.x * v.x + v.y * v.y + v.z * v.z + v.w * v.w;
        #pragma unroll
        for (int off = 32; off > 0; off >>= 1) s += __shfl_down(s, off);
        if (lane == 0) c_sq[k] = s;
    }
    if (gt < 32768) {
        int code = gt & 1023;
        int kg = gt >> 10;
        const float* p = emb + (size_t)code * DD + kg * 8;
        float4 v0 = *(const float4*)p;
        float4 v1 = *(const float4*)(p + 4);
        f16x8 h;
        h[0] = (f16)v0.x; h[1] = (f16)v0.y; h[2] = (f16)v0.z; h[3] = (f16)v0.w;
        h[4] = (f16)v1.x; h[5] = (f16)v1.y; h[6] = (f16)v1.z; h[7] = (f16)v1.w;
        *(f16x8*)(emb_h + (size_t)gt * 8) = h;
    }
}

// ---------------------------------------------------------------------------
// Fused main (R5 structure, proven no-spill at VGPR 52):
// dist (MFMA) + packed-int argmin + loss-from-score + Qh-LDS gather +
// last-block finalize.  Block = 64 rows x 512 threads, grid 512.
// R7 change: STREAMING traffic (z reads, out writes) is non-temporal so the
// 512KB emb_h table stays L2-resident -> B-fragment loads at L2 latency.
// ---------------------------------------------------------------------------
__global__ __launch_bounds__(512, 4)
void vq_main_kernel(const float* __restrict__ z, const float* __restrict__ emb,
                    const f16* __restrict__ emb_h, const float* __restrict__ c_sq,
                    int* __restrict__ counts, float* __restrict__ loss_acc,
                    unsigned* __restrict__ done, float* __restrict__ out,
                    float* __restrict__ out_tail) {
    __shared__ __align__(16) char smem_raw[66560]; // z_s (A/B) then Qh (C)
    __shared__ int   bl_key[8][64];
    __shared__ float zsq_part[8][64];
    __shared__ int   idx_s[64];
    __shared__ float wsum[8];
    __shared__ int   last_flag;

    f16* z_s = (f16*)smem_raw;      // [kg 32][row 64][8]
    float* Qh = (float*)smem_raw;   // [row 64][260]

    const int tid = threadIdx.x;
    const int n0 = blockIdx.x * 64;
    const int b = n0 >> 10;
    const int hw0 = n0 & 1023;

    // ---- Phase A: stage z tile fp16 + per-row ||z||^2 (non-temporal reads) ----
    {
        const int r = tid & 63;
        const int kq = tid >> 6;  // 0..7
        const float* zp = z + (size_t)b * (DD * 1024) + hw0 + r;
        float sq = 0.f;
        #pragma unroll
        for (int it = 0; it < 4; ++it) {
            int kg = kq * 4 + it;
            f16x8 hv;
            #pragma unroll
            for (int j = 0; j < 8; ++j) {
                float v = __builtin_nontemporal_load(zp + (size_t)(kg * 8 + j) * 1024);
                sq += v * v;
                hv[j] = (f16)v;
            }
            *(f16x8*)&z_s[(kg * 64 + r) * 8] = hv;
        }
        zsq_part[kq][r] = sq;
    }
    __syncthreads();

    const int m = tid & 31;        // code-lane within 32-tile
    const int h = (tid >> 5) & 1;  // k-half
    const int w = tid >> 6;        // wave id 0..7

    int bk[32];
    #pragma unroll
    for (int s = 0; s < 32; ++s) bk[s] = 0x7FFFFFFF;

    // ---- Phase B: MFMA + running packed argmin ----
    for (int c = 0; c < 4; ++c) {
        const int cb = w * 128 + c * 32;
        const int code = cb + m;
        const f16* ebp = emb_h + (size_t)h * 8192 + (size_t)code * 8;

        f32x16 acc0, acc1;
        #pragma unroll
        for (int i = 0; i < 16; ++i) { acc0[i] = 0.f; acc1[i] = 0.f; }

        #pragma unroll 4
        for (int ks = 0; ks < 16; ++ks) {
            const f16* za = z_s + (2 * ks + h) * 512 + m * 8;
            f16x8 a0 = *(const f16x8*)(za);          // rows m
            f16x8 a1 = *(const f16x8*)(za + 256);    // rows m+32
            f16x8 b0 = *(const f16x8*)(ebp + (size_t)ks * 16384);
            acc0 = __builtin_amdgcn_mfma_f32_32x32x16_f16(a0, b0, acc0, 0, 0, 0);
            acc1 = __builtin_amdgcn_mfma_f32_32x32x16_f16(a1, b0, acc1, 0, 0, 0);
        }

        const float cs = c_sq[code];
        #pragma unroll
        for (int reg = 0; reg < 16; ++reg) {
            float s0 = fmaf(-2.f, acc0[reg], cs);
            float s1 = fmaf(-2.f, acc1[reg], cs);
            int k0 = (int)(s0 * KEY_SCALE) * 1024 + code;
            int k1 = (int)(s1 * KEY_SCALE) * 1024 + code;
            bk[reg] = min(bk[reg], k0);
            bk[16 + reg] = min(bk[16 + reg], k1);
        }
    }

    // butterfly min across 32 lanes of each half
    #pragma unroll
    for (int s = 0; s < 32; ++s) {
        int k = bk[s];
        #pragma unroll
        for (int d = 16; d >= 1; d >>= 1) k = min(k, __shfl_xor(k, d));
        bk[s] = k;
    }
    if (m == 0) {
        #pragma unroll
        for (int s = 0; s < 32; ++s) {
            int rt = s >> 4, reg = s & 15;
            int row = rt * 32 + (reg & 3) + 8 * (reg >> 2) + 4 * h;
            bl_key[w][row] = bk[s];
        }
    }
    __syncthreads();

    // combine 8 waves -> idx, hist, loss-from-score
    if (tid < 64) {
        int k = bl_key[0][tid];
        #pragma unroll
        for (int w2 = 1; w2 < 8; ++w2) k = min(k, bl_key[w2][tid]);
        int i = k & 1023;               // low 10 bits = code
        idx_s[tid] = i;
        atomicAdd(&counts[i], 1);
        float zq = 0.f;
        #pragma unroll
        for (int p = 0; p < 8; ++p) zq += zsq_part[p][tid];
        float lr = (float)(k >> 10) * KEY_INV + zq;  // score_min + ||z||^2
        #pragma unroll
        for (int off = 32; off > 0; off >>= 1) lr += __shfl_down(lr, off);
        if (tid == 0) atomicAdd(loss_acc, lr);
    }
    __syncthreads();

    // ---- Phase C1: Qh[r][c] = emb[idx[r]][c] fp32, stride 260 ----
    {
        int r = tid & 63;
        int part = tid >> 6;  // 0..7 -> 32 channels each
        const float* ep = emb + (size_t)idx_s[r] * DD + part * 32;
        float* qrow = Qh + r * 260 + part * 32;
        #pragma unroll
        for (int g = 0; g < 8; ++g)
            *(float4*)(qrow + g * 4) = *(const float4*)(ep + g * 4);
    }
    __syncthreads();

    // ---- Phase C2: coalesced channel-major non-temporal writes ----
    {
        int r = tid & 63;
        const float* qr = Qh + r * 260;
        const size_t base = (size_t)b * (DD * 1024) + hw0 + r;
        #pragma unroll
        for (int g = 0; g < 8; ++g) {
            int c0 = w * 32 + g * 4;
            float4 v = *(const float4*)(qr + c0);
            __builtin_nontemporal_store(v.x, out + base + (size_t)c0 * 1024);
            __builtin_nontemporal_store(v.y, out + base + (size_t)(c0 + 1) * 1024);
            __builtin_nontemporal_store(v.z, out + base + (size_t)(c0 + 2) * 1024);
            __builtin_nontemporal_store(v.w, out + base + (size_t)(c0 + 3) * 1024);
        }
    }

    // ---- last-block finalize ----
    __syncthreads();
    if (tid == 0) {
        __threadfence();
        last_flag = (atomicAdd(done, 1u) == 511u) ? 1 : 0;
    }
    __syncthreads();
    if (last_flag) {
        __threadfence();
        float s = 0.f;
        for (int k = tid; k < KC; k += 512) {
            int cnt = atomicAdd(&counts[k], 0);
            float p = (float)cnt * (1.0f / (float)NROWS);
            s += p * logf(p + 1e-10f);
        }
        #pragma unroll
        for (int off = 32; off > 0; off >>= 1) s += __shfl_down(s, off);
        if ((tid & 63) == 0) wsum[w] = s;
        __syncthreads();
        if (tid == 0) {
            float ent = 0.f;
            #pragma unroll
            for (int p = 0; p < 8; ++p) ent += wsum[p];
            float ls = atomicAdd(loss_acc, 0.0f);
            out_tail[0] = 1.25f * ls * (1.0f / (float)NELEM);
            out_tail[1] = expf(-ent);
        }
    }
}

// ---------------------------------------------------------------------------
extern "C" void kernel_launch(void* const* d_in, const int* in_sizes, int n_in,
                              void* d_out, int out_size, void* d_ws, size_t ws_size,
                              hipStream_t stream) {
    const float* z = (const float*)d_in[0];    // (32,256,32,32)
    const float* emb = (const float*)d_in[1];  // (1024,256)
    float* out = (float*)d_out;                // 8388608 + 2

    char* wsb = (char*)d_ws;
    f16* emb_h = (f16*)wsb;
    float* c_sq = (float*)(wsb + 524288);
    int* counts = (int*)(wsb + 528384);
    float* loss_acc = (float*)(wsb + 532480);
    unsigned* done = (unsigned*)(wsb + 532484);

    hipLaunchKernelGGL(vq_prep_kernel, dim3(256), dim3(256), 0, stream,
                       emb, emb_h, c_sq, counts, loss_acc, done);
    hipLaunchKernelGGL(vq_main_kernel, dim3(512), dim3(512), 0, stream,
                       z, emb, emb_h, c_sq, counts, loss_acc, done, out, out + NELEM);
}

// Round 8
// 133.099 us; speedup vs baseline: 1.3849x; 1.0166x over previous
//
#include <hip/hip_runtime.h>
#include <math.h>

// Problem constants
#define KC 1024       // num codes
#define DD 256        // embedding dim
#define NROWS 32768   // 32 * 32 * 32 (B*H*W)
#define NELEM 8388608 // NROWS * DD

typedef _Float16 f16;
typedef __attribute__((ext_vector_type(8))) _Float16 f16x8;
typedef __attribute__((ext_vector_type(16))) float f32x16;

#define KEY_SCALE 2097152.0f   // 2^21; |score| <= ~0.63 -> |ikey| < 2^21
#define KEY_INV   (1.0f / 2097152.0f)

// ---------------------------------------------------------------------------
// prep: zero counts/loss/done + c_sq (exact fp32) + emb -> fp16 swizzled
// grid 256 x 256.  emb_h layout: [kg 32][code 1024][8]
// ---------------------------------------------------------------------------
__global__ void vq_prep_kernel(const float* __restrict__ emb, f16* __restrict__ emb_h,
                               float* __restrict__ c_sq, int* __restrict__ counts,
                               float* __restrict__ loss_acc, unsigned* __restrict__ done) {
    const int tid = threadIdx.x;
    const int gt = blockIdx.x * 256 + tid;
    if (gt < KC) counts[gt] = 0;
    if (gt == 0) { *loss_acc = 0.0f; *done = 0u; }
    {
        int k = blockIdx.x * 4 + (tid >> 6);
        int lane = tid & 63;
        float4 v = *(const float4*)(emb + (size_t)k * DD + lane * 4);
        float s = v.x * v.x + v.y * v.y + v.z * v.z + v.w * v.w;
        #pragma unroll
        for (int off = 32; off > 0; off >>= 1) s += __shfl_down(s, off);
        if (lane == 0) c_sq[k] = s;
    }
    if (gt < 32768) {
        int code = gt & 1023;
        int kg = gt >> 10;
        const float* p = emb + (size_t)code * DD + kg * 8;
        float4 v0 = *(const float4*)p;
        float4 v1 = *(const float4*)(p + 4);
        f16x8 h;
        h[0] = (f16)v0.x; h[1] = (f16)v0.y; h[2] = (f16)v0.z; h[3] = (f16)v0.w;
        h[4] = (f16)v1.x; h[5] = (f16)v1.y; h[6] = (f16)v1.z; h[7] = (f16)v1.w;
        *(f16x8*)(emb_h + (size_t)gt * 8) = h;
    }
}

// ---------------------------------------------------------------------------
// Fused main (R5 structure + 4-deep B-fragment register ring):
// dist (MFMA) + packed-int argmin + loss-from-score + Qh-LDS gather +
// last-block finalize.  Block = 64 rows x 512 threads, grid 512.
// Linear k-step t = c*16+ks; B-frag for step t was loaded at step t-4, so
// vmcnt never drains mid-loop (the fix for the ~450cy exposed L3 latency).
// Ring regs: +16 VGPR over R5's 84 unified -> ~100 <= 128 cap, no spill.
// ---------------------------------------------------------------------------
__global__ __launch_bounds__(512, 4)
void vq_main_kernel(const float* __restrict__ z, const float* __restrict__ emb,
                    const f16* __restrict__ emb_h, const float* __restrict__ c_sq,
                    int* __restrict__ counts, float* __restrict__ loss_acc,
                    unsigned* __restrict__ done, float* __restrict__ out,
                    float* __restrict__ out_tail) {
    __shared__ __align__(16) char smem_raw[66560]; // z_s (A/B) then Qh (C)
    __shared__ int   bl_key[8][64];
    __shared__ float zsq_part[8][64];
    __shared__ int   idx_s[64];
    __shared__ float wsum[8];
    __shared__ int   last_flag;

    f16* z_s = (f16*)smem_raw;      // [kg 32][row 64][8]
    float* Qh = (float*)smem_raw;   // [row 64][260]

    const int tid = threadIdx.x;
    const int n0 = blockIdx.x * 64;
    const int b = n0 >> 10;
    const int hw0 = n0 & 1023;

    const int m = tid & 31;        // code-lane within 32-tile
    const int h = (tid >> 5) & 1;  // k-half (operand layout)
    const int w = tid >> 6;        // wave id 0..7

    // B-frag base: step t -> ebase + (t>>4)*256 + (t&15)*16384   (halfs)
    const f16* ebase = emb_h + (size_t)h * 8192 + (size_t)(w * 128 + m) * 8;

    // ---- Phase A: stage z tile fp16 + per-row ||z||^2 (NT reads) ----
    {
        const int r = tid & 63;
        const int kq = tid >> 6;  // 0..7
        const float* zp = z + (size_t)b * (DD * 1024) + hw0 + r;
        float sq = 0.f;
        #pragma unroll
        for (int it = 0; it < 4; ++it) {
            int kg = kq * 4 + it;
            f16x8 hv;
            #pragma unroll
            for (int j = 0; j < 8; ++j) {
                float v = __builtin_nontemporal_load(zp + (size_t)(kg * 8 + j) * 1024);
                sq += v * v;
                hv[j] = (f16)v;
            }
            *(f16x8*)&z_s[(kg * 64 + r) * 8] = hv;
        }
        zsq_part[kq][r] = sq;
    }

    // preload ring (steps 0..3) -- issued before the barrier, fly through it
    f16x8 bF[4];
    #pragma unroll
    for (int p = 0; p < 4; ++p)
        bF[p] = *(const f16x8*)(ebase + (size_t)p * 16384);

    __syncthreads();

    int bk[32];
    #pragma unroll
    for (int s = 0; s < 32; ++s) bk[s] = 0x7FFFFFFF;

    // ---- Phase B: MFMA + ring prefetch + running packed argmin ----
    for (int c = 0; c < 4; ++c) {
        const int code = w * 128 + c * 32 + m;

        f32x16 acc0, acc1;
        #pragma unroll
        for (int i = 0; i < 16; ++i) { acc0[i] = 0.f; acc1[i] = 0.f; }

        #pragma unroll 4
        for (int ks = 0; ks < 16; ++ks) {
            const int t = c * 16 + ks;
            f16x8 bcur = bF[t & 3];
            // prefetch step t+4 (always in-bounds of emb_h; on the final 4
            // steps the value is loaded but never consumed)
            {
                const int pf = t + 4;
                bF[t & 3] = *(const f16x8*)(ebase + (size_t)((pf >> 4) * 256)
                                                  + (size_t)(pf & 15) * 16384);
            }
            const f16* za = z_s + (2 * ks + h) * 512 + m * 8;
            f16x8 a0 = *(const f16x8*)(za);          // rows m
            f16x8 a1 = *(const f16x8*)(za + 256);    // rows m+32
            acc0 = __builtin_amdgcn_mfma_f32_32x32x16_f16(a0, bcur, acc0, 0, 0, 0);
            acc1 = __builtin_amdgcn_mfma_f32_32x32x16_f16(a1, bcur, acc1, 0, 0, 0);
        }

        const float cs = c_sq[code];
        #pragma unroll
        for (int reg = 0; reg < 16; ++reg) {
            float s0 = fmaf(-2.f, acc0[reg], cs);
            float s1 = fmaf(-2.f, acc1[reg], cs);
            int k0 = (int)(s0 * KEY_SCALE) * 1024 + code;
            int k1 = (int)(s1 * KEY_SCALE) * 1024 + code;
            bk[reg] = min(bk[reg], k0);
            bk[16 + reg] = min(bk[16 + reg], k1);
        }
    }

    // butterfly min across 32 lanes of each half
    #pragma unroll
    for (int s = 0; s < 32; ++s) {
        int k = bk[s];
        #pragma unroll
        for (int d = 16; d >= 1; d >>= 1) k = min(k, __shfl_xor(k, d));
        bk[s] = k;
    }
    if (m == 0) {
        #pragma unroll
        for (int s = 0; s < 32; ++s) {
            int rt = s >> 4, reg = s & 15;
            int row = rt * 32 + (reg & 3) + 8 * (reg >> 2) + 4 * h;
            bl_key[w][row] = bk[s];
        }
    }
    __syncthreads();

    // combine 8 waves -> idx, hist, loss-from-score
    if (tid < 64) {
        int k = bl_key[0][tid];
        #pragma unroll
        for (int w2 = 1; w2 < 8; ++w2) k = min(k, bl_key[w2][tid]);
        int i = k & 1023;               // low 10 bits = code
        idx_s[tid] = i;
        atomicAdd(&counts[i], 1);
        float zq = 0.f;
        #pragma unroll
        for (int p = 0; p < 8; ++p) zq += zsq_part[p][tid];
        float lr = (float)(k >> 10) * KEY_INV + zq;  // score_min + ||z||^2
        #pragma unroll
        for (int off = 32; off > 0; off >>= 1) lr += __shfl_down(lr, off);
        if (tid == 0) atomicAdd(loss_acc, lr);
    }
    __syncthreads();

    // ---- Phase C1: Qh[r][c] = emb[idx[r]][c] fp32, stride 260 ----
    {
        int r = tid & 63;
        int part = tid >> 6;  // 0..7 -> 32 channels each
        const float* ep = emb + (size_t)idx_s[r] * DD + part * 32;
        float* qrow = Qh + r * 260 + part * 32;
        #pragma unroll
        for (int g = 0; g < 8; ++g)
            *(float4*)(qrow + g * 4) = *(const float4*)(ep + g * 4);
    }
    __syncthreads();

    // ---- Phase C2: coalesced channel-major non-temporal writes ----
    {
        int r = tid & 63;
        const float* qr = Qh + r * 260;
        const size_t base = (size_t)b * (DD * 1024) + hw0 + r;
        #pragma unroll
        for (int g = 0; g < 8; ++g) {
            int c0 = w * 32 + g * 4;
            float4 v = *(const float4*)(qr + c0);
            __builtin_nontemporal_store(v.x, out + base + (size_t)c0 * 1024);
            __builtin_nontemporal_store(v.y, out + base + (size_t)(c0 + 1) * 1024);
            __builtin_nontemporal_store(v.z, out + base + (size_t)(c0 + 2) * 1024);
            __builtin_nontemporal_store(v.w, out + base + (size_t)(c0 + 3) * 1024);
        }
    }

    // ---- last-block finalize ----
    __syncthreads();
    if (tid == 0) {
        __threadfence();
        last_flag = (atomicAdd(done, 1u) == 511u) ? 1 : 0;
    }
    __syncthreads();
    if (last_flag) {
        __threadfence();
        float s = 0.f;
        for (int k = tid; k < KC; k += 512) {
            int cnt = atomicAdd(&counts[k], 0);
            float p = (float)cnt * (1.0f / (float)NROWS);
            s += p * logf(p + 1e-10f);
        }
        #pragma unroll
        for (int off = 32; off > 0; off >>= 1) s += __shfl_down(s, off);
        if ((tid & 63) == 0) wsum[w] = s;
        __syncthreads();
        if (tid == 0) {
            float ent = 0.f;
            #pragma unroll
            for (int p = 0; p < 8; ++p) ent += wsum[p];
            float ls = atomicAdd(loss_acc, 0.0f);
            out_tail[0] = 1.25f * ls * (1.0f / (float)NELEM);
            out_tail[1] = expf(-ent);
        }
    }
}

// ---------------------------------------------------------------------------
extern "C" void kernel_launch(void* const* d_in, const int* in_sizes, int n_in,
                              void* d_out, int out_size, void* d_ws, size_t ws_size,
                              hipStream_t stream) {
    const float* z = (const float*)d_in[0];    // (32,256,32,32)
    const float* emb = (const float*)d_in[1];  // (1024,256)
    float* out = (float*)d_out;                // 8388608 + 2

    char* wsb = (char*)d_ws;
    f16* emb_h = (f16*)wsb;
    float* c_sq = (float*)(wsb + 524288);
    int* counts = (int*)(wsb + 528384);
    float* loss_acc = (float*)(wsb + 532480);
    unsigned* done = (unsigned*)(wsb + 532484);

    hipLaunchKernelGGL(vq_prep_kernel, dim3(256), dim3(256), 0, stream,
                       emb, emb_h, c_sq, counts, loss_acc, done);
    hipLaunchKernelGGL(vq_main_kernel, dim3(512), dim3(512), 0, stream,
                       z, emb, emb_h, c_sq, counts, loss_acc, done, out, out + NELEM);
}